// Round 14
// baseline (338.024 us; speedup 1.0000x reference)
//
#include <hip/hip_runtime.h>
#include <stdint.h>

#define N_NODES 50000
#define N_EDGES 800000
#define DIM     128
#define TOT     (N_NODES * DIM)   // 6,400,000
#define NB   196                 // dst buckets: dst>>8
#define CHUNK 8192               // edges per histogram/scatter block
#define NBLK 98                  // ceil(800000/8192)
#define GCAP 4096                // LDS edge cap for gather blocks (mean 1024 @64 nodes)
#define G3CAP 8192               // LDS edge cap for gather3 blocks (mean 4096)
#define XBLKS (TOT / 4 / 256)    // 6250

typedef __attribute__((ext_vector_type(8))) unsigned short ushort8_t;
typedef __attribute__((ext_vector_type(8))) short bfrag;    // 8 bf16 = 4 VGPR
typedef __attribute__((ext_vector_type(4))) float f32x4;

// ---------------- Threefry-2x32 (exact JAX 20-round) ----------------
__host__ __device__ inline void threefry2x32(uint32_t k0, uint32_t k1,
                                             uint32_t x0, uint32_t x1,
                                             uint32_t& o0, uint32_t& o1) {
    uint32_t ks0 = k0, ks1 = k1, ks2 = k0 ^ k1 ^ 0x1BD11BDAu;
    uint32_t v0 = x0 + ks0, v1 = x1 + ks1;
#define TF_R(r) { v0 += v1; v1 = (v1 << (r)) | (v1 >> (32 - (r))); v1 ^= v0; }
    TF_R(13) TF_R(15) TF_R(26) TF_R(6)
    v0 += ks1; v1 += ks2 + 1u;
    TF_R(17) TF_R(29) TF_R(16) TF_R(24)
    v0 += ks2; v1 += ks0 + 2u;
    TF_R(13) TF_R(15) TF_R(26) TF_R(6)
    v0 += ks0; v1 += ks1 + 3u;
    TF_R(17) TF_R(29) TF_R(16) TF_R(24)
    v0 += ks1; v1 += ks2 + 4u;
    TF_R(13) TF_R(15) TF_R(26) TF_R(6)
    v0 += ks2; v1 += ks0 + 5u;
#undef TF_R
    o0 = v0; o1 = v1;
}

__device__ inline float drop_scale(uint32_t kk0, uint32_t kk1, uint32_t i) {
    uint32_t b0, b1;
    threefry2x32(kk0, kk1, 0u, i, b0, b1);
    uint32_t bits = b0 ^ b1;               // partitionable 32-bit path (verified R0)
    return (bits >> 31) ? 0.0f : 2.0f;     // keep iff u < 0.5 iff top bit 0
}

__device__ inline float bf2f(ushort u) {
    return __uint_as_float(((uint32_t)u) << 16);
}
__device__ inline ushort f2bf_rne(float f) {
    uint32_t bits = __float_as_uint(f);
    uint32_t lsb = (bits >> 16) & 1u;
    bits += 0x7fffu + lsb;                 // round-to-nearest-even
    return (ushort)(bits >> 16);
}

// ---------------- fused prep: x->bf16, W1/W2 transpose, dst histogram --------
__global__ __launch_bounds__(256) void k_prep(const float* __restrict__ x,
                                              const float* __restrict__ W1,
                                              const float* __restrict__ W2,
                                              ushort* __restrict__ Xb,
                                              ushort* __restrict__ W1t,
                                              ushort* __restrict__ W2t,
                                              const int* __restrict__ dst,
                                              uint32_t* __restrict__ hist) {
    __shared__ uint32_t h[NB];
    int b = blockIdx.x;
    int t = threadIdx.x;
    if (b < XBLKS) {
        int i = b * 256 + t;
        float4 v = ((const float4*)x)[i];
        ushort4 o;
        o.x = f2bf_rne(v.x); o.y = f2bf_rne(v.y);
        o.z = f2bf_rne(v.z); o.w = f2bf_rne(v.w);
        ((ushort4*)Xb)[i] = o;
    } else if (b < XBLKS + 128) {
        int j = (b - XBLKS) * 256 + t;             // 0..32767
        const float* W = (j < DIM * DIM) ? W1 : W2;
        ushort* Wt = (j < DIM * DIM) ? W1t : W2t;
        int i = j & (DIM * DIM - 1);
        int k = i >> 7, n = i & 127;
        Wt[n * DIM + k] = f2bf_rne(W[k * DIM + n]);
    } else {
        int hb = b - XBLKS - 128;                  // 0..NBLK-1
        if (t < NB) h[t] = 0u;
        __syncthreads();
        int base = hb * CHUNK;
        #pragma unroll
        for (int i = 0; i < CHUNK / 256; ++i) {
            int e = base + i * 256 + t;
            if (e < N_EDGES) atomicAdd(&h[((uint32_t)dst[e]) >> 8], 1u);
        }
        __syncthreads();
        if (t < NB) hist[(size_t)t * NBLK + hb] = h[t];   // transposed layout
    }
}

// ---------------- phase B: offsets (per-thread contiguous stream) ------------
__global__ void k_bscan(uint32_t* __restrict__ hist, uint32_t* __restrict__ bb) {
    __shared__ uint32_t cnt[256];
    int t = threadIdx.x;
    uint32_t running = 0;
    if (t < NB) {
        uint32_t* hp = hist + (size_t)t * NBLK;
        for (int blk = 0; blk < NBLK; ++blk) {
            uint32_t c = hp[blk];
            hp[blk] = running;
            running += c;
        }
    }
    cnt[t] = (t < NB) ? running : 0u;
    __syncthreads();
    for (int off = 1; off < 256; off <<= 1) {
        uint32_t x = (t >= off) ? cnt[t - off] : 0u;
        __syncthreads();
        cnt[t] += x;
        __syncthreads();
    }
    uint32_t incl = cnt[t];
    uint32_t base = incl - ((t < NB) ? running : 0u);
    if (t < NB) bb[t] = base;
    if (t == NB - 1) bb[NB] = incl;
    __syncthreads();
    if (t < NB) {
        uint32_t* hp = hist + (size_t)t * NBLK;
        for (int blk = 0; blk < NBLK; ++blk)
            hp[blk] += base;
    }
}

// ---------------- phase C: scatter packed (dlow8,src16) ----------------
__global__ __launch_bounds__(256) void k_scatter(const int* __restrict__ src,
                                                 const int* __restrict__ dst,
                                                 const uint32_t* __restrict__ hist,
                                                 uint32_t* __restrict__ packed) {
    __shared__ uint32_t cur[NB];
    int t = threadIdx.x;
    int blk = blockIdx.x;
    if (t < NB) cur[t] = hist[(size_t)t * NBLK + blk];
    __syncthreads();
    int base = blk * CHUNK;
    #pragma unroll
    for (int i = 0; i < CHUNK / 256; ++i) {
        int e = base + i * 256 + t;
        if (e < N_EDGES) {
            uint32_t d = (uint32_t)dst[e];
            uint32_t s = (uint32_t)src[e];
            uint32_t b = d >> 8;
            uint32_t pos = atomicAdd(&cur[b], 1u);
            packed[pos] = ((d & 255u) << 16) | s;
        }
    }
}

// ---------------- phase D: per-bucket exact CSR + row + dis ----------------
__global__ __launch_bounds__(256) void k_fill(const uint32_t* __restrict__ bb,
                                              const uint32_t* __restrict__ packed,
                                              uint32_t* __restrict__ row,
                                              float* __restrict__ dis,
                                              ushort* __restrict__ col16) {
    __shared__ uint32_t sdeg[256];
    __shared__ uint32_t scan[256];
    __shared__ uint32_t cur[256];
    int b = blockIdx.x;
    int t = threadIdx.x;
    uint32_t base = bb[b], n = bb[b + 1] - base;
    sdeg[t] = 0u;
    __syncthreads();
    uint32_t mine[24]; int cnt = 0;
    for (uint32_t i = t; i < n; i += 256) {
        uint32_t u = packed[base + i];
        mine[cnt++] = u;
        atomicAdd(&sdeg[u >> 16], 1u);
    }
    __syncthreads();
    uint32_t myd = sdeg[t];
    scan[t] = myd;
    __syncthreads();
    for (int off = 1; off < 256; off <<= 1) {
        uint32_t x = (t >= off) ? scan[t - off] : 0u;
        __syncthreads();
        scan[t] += x;
        __syncthreads();
    }
    uint32_t excl = scan[t] - myd;
    cur[t] = excl;
    int v = b * 256 + t;
    if (v <= N_NODES) row[v] = base + excl;
    if (v < N_NODES)  dis[v] = 1.0f / sqrtf((float)(myd + 1u));
    __syncthreads();
    for (int j = 0; j < cnt; ++j) {
        uint32_t u = mine[j];
        uint32_t pos = base + atomicAdd(&cur[u >> 16], 1u);
        col16[pos] = (ushort)(u & 0xffffu);
    }
}

// ---------------- MFMA bf16 GEMM: H = X @ W, scaled bf16, 32-feat-pair out ---
// Hb[fp][v][32], fp in [0,4). [m89/m91 verified mapping; passed R11]
__global__ __launch_bounds__(256) void k_gemm_mfma(const ushort* __restrict__ Xb,
                                                   const ushort* __restrict__ Wt,
                                                   const float* __restrict__ dis,
                                                   ushort* __restrict__ Hb) {
    int tid = threadIdx.x;
    int w = tid >> 6, lane = tid & 63;
    int m0 = blockIdx.x * 128 + w * 32;
    int lrow = lane & 15, quad = lane >> 4;
    f32x4 acc[2][8] = {};
    for (int kt = 0; kt < DIM; kt += 32) {
        bfrag a[2], b[8];
        #pragma unroll
        for (int t = 0; t < 2; ++t) {
            int m = m0 + t * 16 + lrow;
            if (m >= N_NODES) m = 0;
            a[t] = *(const bfrag*)(Xb + (size_t)m * DIM + kt + quad * 8);
        }
        #pragma unroll
        for (int c = 0; c < 8; ++c) {
            int n = c * 16 + lrow;
            b[c] = *(const bfrag*)(Wt + (size_t)n * DIM + kt + quad * 8);
        }
        #pragma unroll
        for (int t = 0; t < 2; ++t)
            #pragma unroll
            for (int c = 0; c < 8; ++c)
                acc[t][c] = __builtin_amdgcn_mfma_f32_16x16x32_bf16(a[t], b[c], acc[t][c], 0, 0, 0);
    }
    #pragma unroll
    for (int t = 0; t < 2; ++t) {
        #pragma unroll
        for (int r = 0; r < 4; ++r) {
            int rowi = m0 + t * 16 + quad * 4 + r;
            if (rowi < N_NODES) {
                float dv = dis[rowi];
                #pragma unroll
                for (int c = 0; c < 8; ++c) {
                    int feat = c * 16 + lrow;
                    int fp = feat >> 5, off = feat & 31;
                    Hb[((size_t)fp * N_NODES + rowi) * 32 + off] = f2bf_rne(acc[t][c][r] * dv);
                }
            }
        }
    }
}

// ---------------- fused gather + bias + leaky + dropout (layer 1) ------------
// Block (fp = blockIdx&3 -> 32-feat pair, c): 64 nodes; thread=(node, 8-feat q).
// 4 adjacent lanes read one 64B line per edge (halves L2 transactions vs R13).
__global__ __launch_bounds__(256) void k_gather(const uint32_t* __restrict__ row,
                                                const ushort* __restrict__ col16,
                                                const float* __restrict__ dis,
                                                const ushort* __restrict__ Hb,
                                                const float* __restrict__ bias,
                                                ushort* __restrict__ OUTb,
                                                uint32_t kk0, uint32_t kk1) {
    __shared__ ushort scol[GCAP];
    __shared__ uint32_t srow[65];
    int fp = blockIdx.x & 3;
    int c = blockIdx.x >> 2;
    int tid = threadIdx.x;
    int nbase = c * 64;
    int nend = nbase + 64; if (nend > N_NODES) nend = N_NODES;
    int nloc = nend - nbase;
    for (int i = tid; i <= nloc; i += 256) srow[i] = row[nbase + i];
    __syncthreads();
    uint32_t eLo = srow[0];
    uint32_t count = srow[nloc] - eLo;
    bool staged = count <= GCAP;
    if (staged) {
        for (uint32_t i = tid; i < count; i += 256) scol[i] = col16[eLo + i];
    }
    __syncthreads();

    int nl = tid >> 2;                 // node in block
    int q  = tid & 3;                  // 8-feat quarter of the 32-feat pair
    int v = nbase + nl;
    if (v >= N_NODES) return;
    const ushort* Hf = Hb + (size_t)fp * N_NODES * 32;
    ushort8_t hv = *((const ushort8_t*)(Hf + (size_t)v * 32 + q * 8));
    float acc[8];
    #pragma unroll
    for (int j = 0; j < 8; ++j) acc[j] = bf2f(hv[j]);

    uint32_t e0 = srow[nl] - eLo, e1 = srow[nl + 1] - eLo;
    uint32_t e = e0;
    if (staged) {
        for (; e + 4 <= e1; e += 4) {
            uint32_t s0 = scol[e], s1 = scol[e + 1], s2 = scol[e + 2], s3 = scol[e + 3];
            ushort8_t h0 = *((const ushort8_t*)(Hf + (size_t)s0 * 32 + q * 8));
            ushort8_t h1 = *((const ushort8_t*)(Hf + (size_t)s1 * 32 + q * 8));
            ushort8_t h2 = *((const ushort8_t*)(Hf + (size_t)s2 * 32 + q * 8));
            ushort8_t h3 = *((const ushort8_t*)(Hf + (size_t)s3 * 32 + q * 8));
            #pragma unroll
            for (int j = 0; j < 8; ++j)
                acc[j] += (bf2f(h0[j]) + bf2f(h1[j])) + (bf2f(h2[j]) + bf2f(h3[j]));
        }
        for (; e < e1; ++e) {
            uint32_t s0 = scol[e];
            ushort8_t h0 = *((const ushort8_t*)(Hf + (size_t)s0 * 32 + q * 8));
            #pragma unroll
            for (int j = 0; j < 8; ++j) acc[j] += bf2f(h0[j]);
        }
    } else {
        for (; e < e1; ++e) {
            uint32_t s0 = col16[eLo + e];
            ushort8_t h0 = *((const ushort8_t*)(Hf + (size_t)s0 * 32 + q * 8));
            #pragma unroll
            for (int j = 0; j < 8; ++j) acc[j] += bf2f(h0[j]);
        }
    }

    float dv = dis[v];
    int cbase = fp * 32 + q * 8;
    uint32_t ibase = (uint32_t)(v * DIM + cbase);
    ushort8_t o;
    #pragma unroll
    for (int j = 0; j < 8; ++j) {
        float z = acc[j] * dv + bias[cbase + j];
        z = (z >= 0.f) ? z : 0.01f * z;
        z *= drop_scale(kk0, kk1, ibase + j);
        o[j] = f2bf_rne(z);
    }
    *((ushort8_t*)(OUTb + (size_t)v * DIM + cbase)) = o;
}

// ---------------- layer-2 gather with FUSED classifier partial dot -----------
// Same walk; epilogue computes z (bias+leaky+dropout), then partial z.W3 and
// atomically accumulates dis-scaled partials into h3s[2v..2v+1].
__global__ __launch_bounds__(256) void k_gather_cls(const uint32_t* __restrict__ row,
                                                    const ushort* __restrict__ col16,
                                                    const float* __restrict__ dis,
                                                    const ushort* __restrict__ Hb,
                                                    const float* __restrict__ bias,
                                                    const float* __restrict__ W3,
                                                    float* __restrict__ h3s,
                                                    uint32_t kk0, uint32_t kk1) {
    __shared__ ushort scol[GCAP];
    __shared__ uint32_t srow[65];
    __shared__ float sW3[256];
    int fp = blockIdx.x & 3;
    int c = blockIdx.x >> 2;
    int tid = threadIdx.x;
    sW3[tid] = W3[tid];                       // 128x2 = 256 floats
    int nbase = c * 64;
    int nend = nbase + 64; if (nend > N_NODES) nend = N_NODES;
    int nloc = nend - nbase;
    for (int i = tid; i <= nloc; i += 256) srow[i] = row[nbase + i];
    __syncthreads();
    uint32_t eLo = srow[0];
    uint32_t count = srow[nloc] - eLo;
    bool staged = count <= GCAP;
    if (staged) {
        for (uint32_t i = tid; i < count; i += 256) scol[i] = col16[eLo + i];
    }
    __syncthreads();

    int nl = tid >> 2;
    int q  = tid & 3;
    int v = nbase + nl;
    if (v >= N_NODES) return;
    const ushort* Hf = Hb + (size_t)fp * N_NODES * 32;
    ushort8_t hv = *((const ushort8_t*)(Hf + (size_t)v * 32 + q * 8));
    float acc[8];
    #pragma unroll
    for (int j = 0; j < 8; ++j) acc[j] = bf2f(hv[j]);

    uint32_t e0 = srow[nl] - eLo, e1 = srow[nl + 1] - eLo;
    uint32_t e = e0;
    if (staged) {
        for (; e + 4 <= e1; e += 4) {
            uint32_t s0 = scol[e], s1 = scol[e + 1], s2 = scol[e + 2], s3 = scol[e + 3];
            ushort8_t h0 = *((const ushort8_t*)(Hf + (size_t)s0 * 32 + q * 8));
            ushort8_t h1 = *((const ushort8_t*)(Hf + (size_t)s1 * 32 + q * 8));
            ushort8_t h2 = *((const ushort8_t*)(Hf + (size_t)s2 * 32 + q * 8));
            ushort8_t h3 = *((const ushort8_t*)(Hf + (size_t)s3 * 32 + q * 8));
            #pragma unroll
            for (int j = 0; j < 8; ++j)
                acc[j] += (bf2f(h0[j]) + bf2f(h1[j])) + (bf2f(h2[j]) + bf2f(h3[j]));
        }
        for (; e < e1; ++e) {
            uint32_t s0 = scol[e];
            ushort8_t h0 = *((const ushort8_t*)(Hf + (size_t)s0 * 32 + q * 8));
            #pragma unroll
            for (int j = 0; j < 8; ++j) acc[j] += bf2f(h0[j]);
        }
    } else {
        for (; e < e1; ++e) {
            uint32_t s0 = col16[eLo + e];
            ushort8_t h0 = *((const ushort8_t*)(Hf + (size_t)s0 * 32 + q * 8));
            #pragma unroll
            for (int j = 0; j < 8; ++j) acc[j] += bf2f(h0[j]);
        }
    }

    float dv = dis[v];
    int cbase = fp * 32 + q * 8;
    uint32_t ibase = (uint32_t)(v * DIM + cbase);
    float a0 = 0.f, a1 = 0.f;
    #pragma unroll
    for (int j = 0; j < 8; ++j) {
        float z = acc[j] * dv + bias[cbase + j];
        z = (z >= 0.f) ? z : 0.01f * z;
        z *= drop_scale(kk0, kk1, ibase + j);
        a0 += z * sW3[(cbase + j) * 2];
        a1 += z * sW3[(cbase + j) * 2 + 1];
    }
    atomicAdd(&h3s[2 * v],     a0 * dv);
    atomicAdd(&h3s[2 * v + 1], a1 * dv);
}

// ---------------- fused layer-3 gather + bias + log_softmax, LDS-staged ------
__global__ __launch_bounds__(256) void k_gather3(const uint32_t* __restrict__ row,
                                                 const ushort* __restrict__ col16,
                                                 const float* __restrict__ dis,
                                                 const float* __restrict__ H3s,
                                                 const float* __restrict__ b3,
                                                 float* __restrict__ out) {
    __shared__ ushort scol[G3CAP];
    __shared__ uint32_t srow[257];
    int tid = threadIdx.x;
    int nbase = blockIdx.x * 256;
    int nend = nbase + 256; if (nend > N_NODES) nend = N_NODES;
    int nloc = nend - nbase;
    for (int i = tid; i <= nloc; i += 256) srow[i] = row[nbase + i];
    __syncthreads();
    uint32_t eLo = srow[0];
    uint32_t count = srow[nloc] - eLo;
    bool staged = count <= G3CAP;
    if (staged) {
        for (uint32_t i = tid; i < count; i += 256) scol[i] = col16[eLo + i];
    }
    __syncthreads();

    int v = nbase + tid;
    if (v >= N_NODES) return;
    const float2* H2 = (const float2*)H3s;
    float2 h = H2[v];
    float z0 = h.x, z1 = h.y;
    uint32_t e0 = srow[tid] - eLo, e1 = srow[tid + 1] - eLo;
    uint32_t e = e0;
    if (staged) {
        for (; e + 2 <= e1; e += 2) {
            float2 ha = H2[scol[e]];
            float2 hb = H2[scol[e + 1]];
            z0 += ha.x + hb.x; z1 += ha.y + hb.y;
        }
        if (e < e1) {
            float2 ha = H2[scol[e]];
            z0 += ha.x; z1 += ha.y;
        }
    } else {
        for (; e < e1; ++e) {
            float2 ha = H2[col16[eLo + e]];
            z0 += ha.x; z1 += ha.y;
        }
    }
    float dv = dis[v];
    z0 = z0 * dv + b3[0];
    z1 = z1 * dv + b3[1];
    float m = fmaxf(z0, z1);
    float lse = m + logf(expf(z0 - m) + expf(z1 - m));
    out[v * 2 + 0] = z0 - lse;
    out[v * 2 + 1] = z1 - lse;
}

extern "C" void kernel_launch(void* const* d_in, const int* in_sizes, int n_in,
                              void* d_out, int out_size, void* d_ws, size_t ws_size,
                              hipStream_t stream) {
    const float* x  = (const float*)d_in[0];
    const int*   ei = (const int*)d_in[1];
    const float* W1 = (const float*)d_in[2];
    const float* b1 = (const float*)d_in[3];
    const float* W2 = (const float*)d_in[4];
    const float* b2 = (const float*)d_in[5];
    const float* W3 = (const float*)d_in[6];
    const float* b3 = (const float*)d_in[7];
    float* out = (float*)d_out;

    const int* src = ei;
    const int* dst = ei + N_EDGES;

    // workspace layout (u32 units) -- all regions disjoint (R10 lesson);
    // h3s gets its OWN region (gather_cls reads Hb while writing h3s).
    uint32_t* wsu = (uint32_t*)d_ws;
    float*    wsf = (float*)d_ws;
    uint32_t* hist   = wsu;                       // [0, 19208)
    uint32_t* bb     = wsu + 19264;               // [19264, 19461)
    uint32_t* row    = wsu + 19584;               // [19584, 69585)
    float*    dis    = wsf + 69632;               // [69632, 119632)
    uint32_t* packed = wsu + 119680;              // [119680, 919680)
    ushort*   col16  = (ushort*)(wsu + 919680);   // [919680, 1319680)
    ushort*   Hb     = (ushort*)(wsu + 1319680);  // [1319680, 4519680)
    ushort*   Xb     = (ushort*)(wsu + 4519680);  // [4519680, 7719680)
    ushort*   Bb     = (ushort*)(wsu + 7719680);  // [7719680, 10919680)
    ushort*   W1t    = (ushort*)(wsu + 10919680); // [10919680, 10927872)
    ushort*   W2t    = (ushort*)(wsu + 10927872); // [10927872, 10936064)
    float*    h3s    = wsf + 10936064;            // [10936064, 11036064)

    // dropout keys: threefry-partitionable fold-like split of key(42) (verified R0)
    uint32_t k1a, k1b, k2a, k2b;
    threefry2x32(0u, 42u, 0u, 0u, k1a, k1b);
    threefry2x32(0u, 42u, 0u, 1u, k2a, k2b);

    hipMemsetAsync(h3s, 0, N_NODES * 2 * sizeof(float), stream);

    // ---- prep (converts + histogram) + CSR counting sort ----
    k_prep<<<XBLKS + 128 + NBLK, 256, 0, stream>>>(x, W1, W2, Xb, W1t, W2t, dst, hist);
    k_bscan<<<1, 256, 0, stream>>>(hist, bb);
    k_scatter<<<NBLK, 256, 0, stream>>>(src, dst, hist, packed);
    k_fill<<<NB, 256, 0, stream>>>(bb, packed, row, dis, col16);

    int ggrid = ((N_NODES + 63) / 64) * 4;               // (fp, 64-node chunk)
    int mgrid = (N_NODES + 127) / 128;                   // 391

    // ---- layer 1: Xb -> Hb(bf16, scaled, 32-feat pairs) -> Bb(bf16) ----
    k_gemm_mfma<<<mgrid, 256, 0, stream>>>(Xb, W1t, dis, Hb);
    k_gather<<<ggrid, 256, 0, stream>>>(row, col16, dis, Hb, b1, Bb, k1a, k1b);

    // ---- layer 2: Bb -> Hb -> (fused classifier) h3s ----
    k_gemm_mfma<<<mgrid, 256, 0, stream>>>(Bb, W2t, dis, Hb);
    k_gather_cls<<<ggrid, 256, 0, stream>>>(row, col16, dis, Hb, b2, W3, h3s, k2a, k2b);

    // ---- layer 3: h3s -> out ----
    k_gather3<<<(N_NODES + 255) / 256, 256, 0, stream>>>(row, col16, dis, h3s, b3, out);
}

// Round 15
// 254.861 us; speedup vs baseline: 1.3263x; 1.3263x over previous
//
#include <hip/hip_runtime.h>
#include <stdint.h>

#define N_NODES 50000
#define N_EDGES 800000
#define DIM     128
#define TOT     (N_NODES * DIM)   // 6,400,000
#define NB   196                 // dst buckets: dst>>8
#define CHUNK 8192               // edges per histogram/scatter block
#define NBLK 98                  // ceil(800000/8192)
#define GCAP 4096                // LDS edge cap for gather blocks (mean 1024 @64 nodes)
#define G3CAP 8192               // LDS edge cap for gather3 blocks (mean 4096)
#define XBLKS (TOT / 4 / 256)    // 6250

typedef __attribute__((ext_vector_type(8))) unsigned short ushort8_t;
typedef __attribute__((ext_vector_type(8))) short bfrag;    // 8 bf16 = 4 VGPR
typedef __attribute__((ext_vector_type(4))) float f32x4;

// ---------------- Threefry-2x32 (exact JAX 20-round) ----------------
__host__ __device__ inline void threefry2x32(uint32_t k0, uint32_t k1,
                                             uint32_t x0, uint32_t x1,
                                             uint32_t& o0, uint32_t& o1) {
    uint32_t ks0 = k0, ks1 = k1, ks2 = k0 ^ k1 ^ 0x1BD11BDAu;
    uint32_t v0 = x0 + ks0, v1 = x1 + ks1;
#define TF_R(r) { v0 += v1; v1 = (v1 << (r)) | (v1 >> (32 - (r))); v1 ^= v0; }
    TF_R(13) TF_R(15) TF_R(26) TF_R(6)
    v0 += ks1; v1 += ks2 + 1u;
    TF_R(17) TF_R(29) TF_R(16) TF_R(24)
    v0 += ks2; v1 += ks0 + 2u;
    TF_R(13) TF_R(15) TF_R(26) TF_R(6)
    v0 += ks0; v1 += ks1 + 3u;
    TF_R(17) TF_R(29) TF_R(16) TF_R(24)
    v0 += ks1; v1 += ks2 + 4u;
    TF_R(13) TF_R(15) TF_R(26) TF_R(6)
    v0 += ks2; v1 += ks0 + 5u;
#undef TF_R
    o0 = v0; o1 = v1;
}

__device__ inline float drop_scale(uint32_t kk0, uint32_t kk1, uint32_t i) {
    uint32_t b0, b1;
    threefry2x32(kk0, kk1, 0u, i, b0, b1);
    uint32_t bits = b0 ^ b1;               // partitionable 32-bit path (verified R0)
    return (bits >> 31) ? 0.0f : 2.0f;     // keep iff u < 0.5 iff top bit 0
}

__device__ inline float bf2f(ushort u) {
    return __uint_as_float(((uint32_t)u) << 16);
}
__device__ inline float bfpair_lo(uint32_t u) { return __uint_as_float(u << 16); }
__device__ inline float bfpair_hi(uint32_t u) { return __uint_as_float(u & 0xffff0000u); }

__device__ inline ushort f2bf_rne(float f) {
    uint32_t bits = __float_as_uint(f);
    uint32_t lsb = (bits >> 16) & 1u;
    bits += 0x7fffu + lsb;                 // round-to-nearest-even
    return (ushort)(bits >> 16);
}

// ---------------- fused prep: x->bf16, W1/W2 transpose, dst histogram --------
__global__ __launch_bounds__(256) void k_prep(const float* __restrict__ x,
                                              const float* __restrict__ W1,
                                              const float* __restrict__ W2,
                                              ushort* __restrict__ Xb,
                                              ushort* __restrict__ W1t,
                                              ushort* __restrict__ W2t,
                                              const int* __restrict__ dst,
                                              uint32_t* __restrict__ hist) {
    __shared__ uint32_t h[NB];
    int b = blockIdx.x;
    int t = threadIdx.x;
    if (b < XBLKS) {
        int i = b * 256 + t;
        float4 v = ((const float4*)x)[i];
        ushort4 o;
        o.x = f2bf_rne(v.x); o.y = f2bf_rne(v.y);
        o.z = f2bf_rne(v.z); o.w = f2bf_rne(v.w);
        ((ushort4*)Xb)[i] = o;
    } else if (b < XBLKS + 128) {
        int j = (b - XBLKS) * 256 + t;             // 0..32767
        const float* W = (j < DIM * DIM) ? W1 : W2;
        ushort* Wt = (j < DIM * DIM) ? W1t : W2t;
        int i = j & (DIM * DIM - 1);
        int k = i >> 7, n = i & 127;
        Wt[n * DIM + k] = f2bf_rne(W[k * DIM + n]);
    } else {
        int hb = b - XBLKS - 128;                  // 0..NBLK-1
        if (t < NB) h[t] = 0u;
        __syncthreads();
        int base = hb * CHUNK;
        #pragma unroll
        for (int i = 0; i < CHUNK / 256; ++i) {
            int e = base + i * 256 + t;
            if (e < N_EDGES) atomicAdd(&h[((uint32_t)dst[e]) >> 8], 1u);
        }
        __syncthreads();
        if (t < NB) hist[(size_t)t * NBLK + hb] = h[t];   // transposed layout
    }
}

// ---------------- phase B: offsets (per-thread contiguous stream) ------------
__global__ void k_bscan(uint32_t* __restrict__ hist, uint32_t* __restrict__ bb) {
    __shared__ uint32_t cnt[256];
    int t = threadIdx.x;
    uint32_t running = 0;
    if (t < NB) {
        uint32_t* hp = hist + (size_t)t * NBLK;
        for (int blk = 0; blk < NBLK; ++blk) {
            uint32_t c = hp[blk];
            hp[blk] = running;
            running += c;
        }
    }
    cnt[t] = (t < NB) ? running : 0u;
    __syncthreads();
    for (int off = 1; off < 256; off <<= 1) {
        uint32_t x = (t >= off) ? cnt[t - off] : 0u;
        __syncthreads();
        cnt[t] += x;
        __syncthreads();
    }
    uint32_t incl = cnt[t];
    uint32_t base = incl - ((t < NB) ? running : 0u);
    if (t < NB) bb[t] = base;
    if (t == NB - 1) bb[NB] = incl;
    __syncthreads();
    if (t < NB) {
        uint32_t* hp = hist + (size_t)t * NBLK;
        for (int blk = 0; blk < NBLK; ++blk)
            hp[blk] += base;
    }
}

// ---------------- phase C: scatter packed (dlow8,src16) ----------------
__global__ __launch_bounds__(256) void k_scatter(const int* __restrict__ src,
                                                 const int* __restrict__ dst,
                                                 const uint32_t* __restrict__ hist,
                                                 uint32_t* __restrict__ packed) {
    __shared__ uint32_t cur[NB];
    int t = threadIdx.x;
    int blk = blockIdx.x;
    if (t < NB) cur[t] = hist[(size_t)t * NBLK + blk];
    __syncthreads();
    int base = blk * CHUNK;
    #pragma unroll
    for (int i = 0; i < CHUNK / 256; ++i) {
        int e = base + i * 256 + t;
        if (e < N_EDGES) {
            uint32_t d = (uint32_t)dst[e];
            uint32_t s = (uint32_t)src[e];
            uint32_t b = d >> 8;
            uint32_t pos = atomicAdd(&cur[b], 1u);
            packed[pos] = ((d & 255u) << 16) | s;
        }
    }
}

// ---------------- phase D: per-bucket exact CSR + row + dis ----------------
__global__ __launch_bounds__(256) void k_fill(const uint32_t* __restrict__ bb,
                                              const uint32_t* __restrict__ packed,
                                              uint32_t* __restrict__ row,
                                              float* __restrict__ dis,
                                              ushort* __restrict__ col16) {
    __shared__ uint32_t sdeg[256];
    __shared__ uint32_t scan[256];
    __shared__ uint32_t cur[256];
    int b = blockIdx.x;
    int t = threadIdx.x;
    uint32_t base = bb[b], n = bb[b + 1] - base;
    sdeg[t] = 0u;
    __syncthreads();
    uint32_t mine[24]; int cnt = 0;
    for (uint32_t i = t; i < n; i += 256) {
        uint32_t u = packed[base + i];
        mine[cnt++] = u;
        atomicAdd(&sdeg[u >> 16], 1u);
    }
    __syncthreads();
    uint32_t myd = sdeg[t];
    scan[t] = myd;
    __syncthreads();
    for (int off = 1; off < 256; off <<= 1) {
        uint32_t x = (t >= off) ? scan[t - off] : 0u;
        __syncthreads();
        scan[t] += x;
        __syncthreads();
    }
    uint32_t excl = scan[t] - myd;
    cur[t] = excl;
    int v = b * 256 + t;
    if (v <= N_NODES) row[v] = base + excl;
    if (v < N_NODES)  dis[v] = 1.0f / sqrtf((float)(myd + 1u));
    __syncthreads();
    for (int j = 0; j < cnt; ++j) {
        uint32_t u = mine[j];
        uint32_t pos = base + atomicAdd(&cur[u >> 16], 1u);
        col16[pos] = (ushort)(u & 0xffffu);
    }
}

// ---------------- MFMA bf16 GEMM: H = X @ W, scaled bf16, 32-feat-pair out ---
// Hb[fp][v][32], fp in [0,4). [m89/m91 verified mapping; passed R11]
__global__ __launch_bounds__(256) void k_gemm_mfma(const ushort* __restrict__ Xb,
                                                   const ushort* __restrict__ Wt,
                                                   const float* __restrict__ dis,
                                                   ushort* __restrict__ Hb) {
    int tid = threadIdx.x;
    int w = tid >> 6, lane = tid & 63;
    int m0 = blockIdx.x * 128 + w * 32;
    int lrow = lane & 15, quad = lane >> 4;
    f32x4 acc[2][8] = {};
    for (int kt = 0; kt < DIM; kt += 32) {
        bfrag a[2], b[8];
        #pragma unroll
        for (int t = 0; t < 2; ++t) {
            int m = m0 + t * 16 + lrow;
            if (m >= N_NODES) m = 0;
            a[t] = *(const bfrag*)(Xb + (size_t)m * DIM + kt + quad * 8);
        }
        #pragma unroll
        for (int c = 0; c < 8; ++c) {
            int n = c * 16 + lrow;
            b[c] = *(const bfrag*)(Wt + (size_t)n * DIM + kt + quad * 8);
        }
        #pragma unroll
        for (int t = 0; t < 2; ++t)
            #pragma unroll
            for (int c = 0; c < 8; ++c)
                acc[t][c] = __builtin_amdgcn_mfma_f32_16x16x32_bf16(a[t], b[c], acc[t][c], 0, 0, 0);
    }
    #pragma unroll
    for (int t = 0; t < 2; ++t) {
        #pragma unroll
        for (int r = 0; r < 4; ++r) {
            int rowi = m0 + t * 16 + quad * 4 + r;
            if (rowi < N_NODES) {
                float dv = dis[rowi];
                #pragma unroll
                for (int c = 0; c < 8; ++c) {
                    int feat = c * 16 + lrow;
                    int fp = feat >> 5, off = feat & 31;
                    Hb[((size_t)fp * N_NODES + rowi) * 32 + off] = f2bf_rne(acc[t][c][r] * dv);
                }
            }
        }
    }
}

// ---------------- fused gather + bias + leaky + dropout ----------------
// Block (fp = blockIdx&3 -> 32-feat pair, c): 64 nodes; thread=(node, 8-feat q).
// 4 adjacent lanes read one 64B line per edge. Output: line-complete 16B stores
// to Bb (NO cross-XCD sub-line scatter -- R14 lesson).
__global__ __launch_bounds__(256) void k_gather(const uint32_t* __restrict__ row,
                                                const ushort* __restrict__ col16,
                                                const float* __restrict__ dis,
                                                const ushort* __restrict__ Hb,
                                                const float* __restrict__ bias,
                                                ushort* __restrict__ OUTb,
                                                uint32_t kk0, uint32_t kk1) {
    __shared__ ushort scol[GCAP];
    __shared__ uint32_t srow[65];
    int fp = blockIdx.x & 3;
    int c = blockIdx.x >> 2;
    int tid = threadIdx.x;
    int nbase = c * 64;
    int nend = nbase + 64; if (nend > N_NODES) nend = N_NODES;
    int nloc = nend - nbase;
    for (int i = tid; i <= nloc; i += 256) srow[i] = row[nbase + i];
    __syncthreads();
    uint32_t eLo = srow[0];
    uint32_t count = srow[nloc] - eLo;
    bool staged = count <= GCAP;
    if (staged) {
        for (uint32_t i = tid; i < count; i += 256) scol[i] = col16[eLo + i];
    }
    __syncthreads();

    int nl = tid >> 2;                 // node in block
    int q  = tid & 3;                  // 8-feat quarter of the 32-feat pair
    int v = nbase + nl;
    if (v >= N_NODES) return;
    const ushort* Hf = Hb + (size_t)fp * N_NODES * 32;
    ushort8_t hv = *((const ushort8_t*)(Hf + (size_t)v * 32 + q * 8));
    float acc[8];
    #pragma unroll
    for (int j = 0; j < 8; ++j) acc[j] = bf2f(hv[j]);

    uint32_t e0 = srow[nl] - eLo, e1 = srow[nl + 1] - eLo;
    uint32_t e = e0;
    if (staged) {
        for (; e + 4 <= e1; e += 4) {
            uint32_t s0 = scol[e], s1 = scol[e + 1], s2 = scol[e + 2], s3 = scol[e + 3];
            ushort8_t h0 = *((const ushort8_t*)(Hf + (size_t)s0 * 32 + q * 8));
            ushort8_t h1 = *((const ushort8_t*)(Hf + (size_t)s1 * 32 + q * 8));
            ushort8_t h2 = *((const ushort8_t*)(Hf + (size_t)s2 * 32 + q * 8));
            ushort8_t h3 = *((const ushort8_t*)(Hf + (size_t)s3 * 32 + q * 8));
            #pragma unroll
            for (int j = 0; j < 8; ++j)
                acc[j] += (bf2f(h0[j]) + bf2f(h1[j])) + (bf2f(h2[j]) + bf2f(h3[j]));
        }
        for (; e < e1; ++e) {
            uint32_t s0 = scol[e];
            ushort8_t h0 = *((const ushort8_t*)(Hf + (size_t)s0 * 32 + q * 8));
            #pragma unroll
            for (int j = 0; j < 8; ++j) acc[j] += bf2f(h0[j]);
        }
    } else {
        for (; e < e1; ++e) {
            uint32_t s0 = col16[eLo + e];
            ushort8_t h0 = *((const ushort8_t*)(Hf + (size_t)s0 * 32 + q * 8));
            #pragma unroll
            for (int j = 0; j < 8; ++j) acc[j] += bf2f(h0[j]);
        }
    }

    float dv = dis[v];
    int cbase = fp * 32 + q * 8;
    uint32_t ibase = (uint32_t)(v * DIM + cbase);
    ushort8_t o;
    #pragma unroll
    for (int j = 0; j < 8; ++j) {
        float z = acc[j] * dv + bias[cbase + j];
        z = (z >= 0.f) ? z : 0.01f * z;
        z *= drop_scale(kk0, kk1, ibase + j);
        o[j] = f2bf_rne(z);
    }
    *((ushort8_t*)(OUTb + (size_t)v * DIM + cbase)) = o;
}

// ---------------- classifier GEMM: (N x 128 bf16) @ (128 x 2 fp32), scaled ----
__global__ void k_gemm_cls(const ushort* __restrict__ Bb, const float* __restrict__ W3,
                           const float* __restrict__ dis, float* __restrict__ O) {
    int v = blockIdx.x * blockDim.x + threadIdx.x;
    if (v >= N_NODES) return;
    const uint32_t* r = (const uint32_t*)(Bb + (size_t)v * DIM);
    float a0 = 0.f, a1 = 0.f;
#pragma unroll 8
    for (int w = 0; w < 64; ++w) {
        uint32_t u = r[w];
        float x0 = bfpair_lo(u), x1 = bfpair_hi(u);
        const float* wp = W3 + w * 4;
        a0 += x0 * wp[0] + x1 * wp[2];
        a1 += x0 * wp[1] + x1 * wp[3];
    }
    float dv = dis[v];
    O[v * 2 + 0] = a0 * dv;
    O[v * 2 + 1] = a1 * dv;
}

// ---------------- fused layer-3 gather + bias + log_softmax, LDS-staged ------
__global__ __launch_bounds__(256) void k_gather3(const uint32_t* __restrict__ row,
                                                 const ushort* __restrict__ col16,
                                                 const float* __restrict__ dis,
                                                 const float* __restrict__ H3s,
                                                 const float* __restrict__ b3,
                                                 float* __restrict__ out) {
    __shared__ ushort scol[G3CAP];
    __shared__ uint32_t srow[257];
    int tid = threadIdx.x;
    int nbase = blockIdx.x * 256;
    int nend = nbase + 256; if (nend > N_NODES) nend = N_NODES;
    int nloc = nend - nbase;
    for (int i = tid; i <= nloc; i += 256) srow[i] = row[nbase + i];
    __syncthreads();
    uint32_t eLo = srow[0];
    uint32_t count = srow[nloc] - eLo;
    bool staged = count <= G3CAP;
    if (staged) {
        for (uint32_t i = tid; i < count; i += 256) scol[i] = col16[eLo + i];
    }
    __syncthreads();

    int v = nbase + tid;
    if (v >= N_NODES) return;
    const float2* H2 = (const float2*)H3s;
    float2 h = H2[v];
    float z0 = h.x, z1 = h.y;
    uint32_t e0 = srow[tid] - eLo, e1 = srow[tid + 1] - eLo;
    uint32_t e = e0;
    if (staged) {
        for (; e + 2 <= e1; e += 2) {
            float2 ha = H2[scol[e]];
            float2 hb = H2[scol[e + 1]];
            z0 += ha.x + hb.x; z1 += ha.y + hb.y;
        }
        if (e < e1) {
            float2 ha = H2[scol[e]];
            z0 += ha.x; z1 += ha.y;
        }
    } else {
        for (; e < e1; ++e) {
            float2 ha = H2[col16[eLo + e]];
            z0 += ha.x; z1 += ha.y;
        }
    }
    float dv = dis[v];
    z0 = z0 * dv + b3[0];
    z1 = z1 * dv + b3[1];
    float m = fmaxf(z0, z1);
    float lse = m + logf(expf(z0 - m) + expf(z1 - m));
    out[v * 2 + 0] = z0 - lse;
    out[v * 2 + 1] = z1 - lse;
}

extern "C" void kernel_launch(void* const* d_in, const int* in_sizes, int n_in,
                              void* d_out, int out_size, void* d_ws, size_t ws_size,
                              hipStream_t stream) {
    const float* x  = (const float*)d_in[0];
    const int*   ei = (const int*)d_in[1];
    const float* W1 = (const float*)d_in[2];
    const float* b1 = (const float*)d_in[3];
    const float* W2 = (const float*)d_in[4];
    const float* b2 = (const float*)d_in[5];
    const float* W3 = (const float*)d_in[6];
    const float* b3 = (const float*)d_in[7];
    float* out = (float*)d_out;

    const int* src = ei;
    const int* dst = ei + N_EDGES;

    // workspace layout (u32 units) -- all regions disjoint (R10 lesson)
    uint32_t* wsu = (uint32_t*)d_ws;
    float*    wsf = (float*)d_ws;
    uint32_t* hist   = wsu;                       // [0, 19208)
    uint32_t* bb     = wsu + 19264;               // [19264, 19461)
    uint32_t* row    = wsu + 19584;               // [19584, 69585)
    float*    dis    = wsf + 69632;               // [69632, 119632)
    uint32_t* packed = wsu + 119680;              // [119680, 919680)
    ushort*   col16  = (ushort*)(wsu + 919680);   // [919680, 1319680)
    ushort*   Hb     = (ushort*)(wsu + 1319680);  // [1319680, 4519680)
    ushort*   Xb     = (ushort*)(wsu + 4519680);  // [4519680, 7719680)
    ushort*   Bb     = (ushort*)(wsu + 7719680);  // [7719680, 10919680)
    ushort*   W1t    = (ushort*)(wsu + 10919680); // [10919680, 10927872)
    ushort*   W2t    = (ushort*)(wsu + 10927872); // [10927872, 10936064)
    float*    h3s    = wsf + 10936064;            // [10936064, 11036064)

    // dropout keys: threefry-partitionable fold-like split of key(42) (verified R0)
    uint32_t k1a, k1b, k2a, k2b;
    threefry2x32(0u, 42u, 0u, 0u, k1a, k1b);
    threefry2x32(0u, 42u, 0u, 1u, k2a, k2b);

    // ---- prep (converts + histogram) + CSR counting sort ----
    k_prep<<<XBLKS + 128 + NBLK, 256, 0, stream>>>(x, W1, W2, Xb, W1t, W2t, dst, hist);
    k_bscan<<<1, 256, 0, stream>>>(hist, bb);
    k_scatter<<<NBLK, 256, 0, stream>>>(src, dst, hist, packed);
    k_fill<<<NB, 256, 0, stream>>>(bb, packed, row, dis, col16);

    int ggrid = ((N_NODES + 63) / 64) * 4;               // (fp, 64-node chunk)
    int mgrid = (N_NODES + 127) / 128;                   // 391

    // ---- layer 1: Xb -> Hb(bf16, scaled, 32-feat pairs) -> Bb(bf16) ----
    k_gemm_mfma<<<mgrid, 256, 0, stream>>>(Xb, W1t, dis, Hb);
    k_gather<<<ggrid, 256, 0, stream>>>(row, col16, dis, Hb, b1, Bb, k1a, k1b);

    // ---- layer 2: Bb -> Hb -> Bb ----
    k_gemm_mfma<<<mgrid, 256, 0, stream>>>(Bb, W2t, dis, Hb);
    k_gather<<<ggrid, 256, 0, stream>>>(row, col16, dis, Hb, b2, Bb, k2a, k2b);

    // ---- layer 3: Bb -> h3s(pre-scaled) -> out ----
    k_gemm_cls<<<(N_NODES + 255) / 256, 256, 0, stream>>>(Bb, W3, dis, h3s);
    k_gather3<<<(N_NODES + 255) / 256, 256, 0, stream>>>(row, col16, dis, h3s, b3, out);
}